// Round 2
// baseline (717.069 us; speedup 1.0000x reference)
//
#include <hip/hip_runtime.h>

// penalty = (1/10) * sum_j trace(cov_j), unbiased (n-1).
// One pass over x: trace_j = (S2_j - sum_d S_{j,d}^2 / n_j) / (n_j - 1).
// Memory-bound: 512 MB x + 4 MB t, read once -> ~82 us floor @ 6.3 TB/s.
//
// Layout trick: one wave64 owns one row (64 lanes x float2 = 512 B), so the
// class label is wave-uniform -> readfirstlane puts it in an SGPR and the
// 10-way class dispatch compiles to scalar branches (only the matching
// 3-VALU body executes). Counts computed in a separate cheap pass over t.

#define NCLS 10
#define DFEAT 128
#define NB 2048               // main-pass blocks
#define BLK 256               // 4 waves/block
#define WPB (BLK / 64)
#define NWAVE (NB * WPB)      // 8192 waves
#define CCOLS (NCLS * 129)    // per class: 128 feature sums + sumsq = 1290
#define CNTB 256              // count-pass blocks

__global__ __launch_bounds__(BLK, 8) void k_partial(const float* __restrict__ x,
                                                    const int* __restrict__ t,
                                                    float* __restrict__ partial,
                                                    int N) {
    const int lane = threadIdx.x & 63;
    const int wid = blockIdx.x * WPB + (threadIdx.x >> 6);
    const float2* __restrict__ xv = (const float2*)x;  // row stride = 64 float2

    float2 s[NCLS];
    float sq[NCLS];
#pragma unroll
    for (int c = 0; c < NCLS; ++c) {
        s[c] = make_float2(0.f, 0.f);
        sq[c] = 0.f;
    }

    // each wave handles row pairs (2w, 2w+1), striding by 2*NWAVE.
    // N is even, so r0 < N implies r0+1 < N.
    for (int r0 = wid * 2; r0 < N; r0 += 2 * NWAVE) {
        const int r1 = r0 + 1;
        float2 v0 = xv[(size_t)r0 * 64 + lane];
        float2 v1 = xv[(size_t)r1 * 64 + lane];
        const int c0 = __builtin_amdgcn_readfirstlane(t[r0]);  // wave-uniform
        const int c1 = __builtin_amdgcn_readfirstlane(t[r1]);
        const float d0 = v0.x * v0.x + v0.y * v0.y;
        const float d1 = v1.x * v1.x + v1.y * v1.y;
#pragma unroll
        for (int c = 0; c < NCLS; ++c)
            if (c0 == c) { s[c].x += v0.x; s[c].y += v0.y; sq[c] += d0; }
#pragma unroll
        for (int c = 0; c < NCLS; ++c)
            if (c1 == c) { s[c].x += v1.x; s[c].y += v1.y; sq[c] += d1; }
    }

    // block reduction: lane L holds features {2L, 2L+1}; 4 waves share via LDS atomics
    __shared__ float smem[CCOLS];
    for (int i = threadIdx.x; i < CCOLS; i += BLK) smem[i] = 0.0f;
    __syncthreads();
#pragma unroll
    for (int c = 0; c < NCLS; ++c) {
        atomicAdd(&smem[c * 129 + lane * 2 + 0], s[c].x);
        atomicAdd(&smem[c * 129 + lane * 2 + 1], s[c].y);
        float q = sq[c];
#pragma unroll
        for (int off = 32; off > 0; off >>= 1) q += __shfl_down(q, off, 64);
        if (lane == 0) atomicAdd(&smem[c * 129 + 128], q);
    }
    __syncthreads();
    // column-major partials for coalesced stage-2 reads
    for (int i = threadIdx.x; i < CCOLS; i += BLK)
        partial[(size_t)i * NB + blockIdx.x] = smem[i];
}

__global__ __launch_bounds__(256) void k_count(const int* __restrict__ t,
                                               float* __restrict__ countpart, int N) {
    __shared__ int h[NCLS];
    if (threadIdx.x < NCLS) h[threadIdx.x] = 0;
    __syncthreads();
    for (int i = blockIdx.x * 256 + threadIdx.x; i < N; i += 256 * CNTB)
        atomicAdd(&h[t[i]], 1);
    __syncthreads();
    if (threadIdx.x < NCLS)
        countpart[threadIdx.x * CNTB + blockIdx.x] = (float)h[threadIdx.x];
}

__global__ __launch_bounds__(64) void k_colsum(const float* __restrict__ partial,
                                               float* __restrict__ totals) {
    const int col = blockIdx.x;
    const float* p = partial + (size_t)col * NB;
    float v = 0.f;
    for (int i = threadIdx.x; i < NB; i += 64) v += p[i];
#pragma unroll
    for (int off = 32; off > 0; off >>= 1) v += __shfl_down(v, off, 64);
    if (threadIdx.x == 0) totals[col] = v;
}

__global__ __launch_bounds__(64) void k_final(const float* __restrict__ totals,
                                              const float* __restrict__ countpart,
                                              float* __restrict__ out) {
    const int lane = threadIdx.x;
    float tr = 0.0f;
    if (lane < NCLS) {
        const float* b = totals + lane * 129;
        float ss = 0.f;
        for (int d = 0; d < DFEAT; ++d) {
            float u = b[d];
            ss += u * u;
        }
        const float S2 = b[128];
        float n = 0.f;
        for (int i = 0; i < CNTB; ++i) n += countpart[lane * CNTB + i];
        tr = (S2 - ss / n) / (n - 1.0f);
    }
#pragma unroll
    for (int off = 32; off > 0; off >>= 1) tr += __shfl_down(tr, off, 64);
    if (lane == 0) out[0] = tr / (float)NCLS;
}

extern "C" void kernel_launch(void* const* d_in, const int* in_sizes, int n_in,
                              void* d_out, int out_size, void* d_ws, size_t ws_size,
                              hipStream_t stream) {
    const float* x = (const float*)d_in[0];
    const int* t = (const int*)d_in[1];
    const int N = in_sizes[1];  // t has N elements; x has N*128

    float* partial = (float*)d_ws;                        // CCOLS * NB
    float* totals = partial + (size_t)CCOLS * NB;         // CCOLS
    float* countpart = totals + CCOLS;                    // NCLS * CNTB
    float* out = (float*)d_out;

    k_partial<<<NB, BLK, 0, stream>>>(x, t, partial, N);
    k_count<<<CNTB, 256, 0, stream>>>(t, countpart, N);
    k_colsum<<<CCOLS, 64, 0, stream>>>(partial, totals);
    k_final<<<1, 64, 0, stream>>>(totals, countpart, out);
}